// Round 3
// baseline (6331.845 us; speedup 1.0000x reference)
//
#include <hip/hip_runtime.h>
#include <math.h>
#include <type_traits>

// Problem constants
#define NB 512     // batch
#define HD 512     // hidden
#define CD 64      // in channels
#define TD 168     // encode length
#define DSTEPS 24  // decoder steps
#define OUTC 64    // out channels
#define GATES 2048 // 4*HD
#define KWE (HD + CD)   // encoder K = 576
#define NCHE (KWE / 32) // 18 chunks
#define NCHD (HD / 32)  // 16 chunks

typedef __attribute__((ext_vector_type(8))) short bf16x8;
typedef __attribute__((ext_vector_type(4))) float f32x4;

__device__ __forceinline__ float sigmf(float x) { return 1.0f / (1.0f + expf(-x)); }
__device__ __forceinline__ float bf2f(unsigned short h) {
    return __uint_as_float(((unsigned)h) << 16);
}
__device__ __forceinline__ unsigned short f2bf(float x) {  // round-to-nearest-even
    unsigned u = __float_as_uint(x);
    return (unsigned short)((u + 0x7fffu + ((u >> 16) & 1u)) >> 16);
}

// ---------------------------------------------------------------------------
// Weight prep: split f32 into bf16 hi/lo, permuted + fragment-ready.
// Per-jt slab layout: elem [(ch*4 + ks)*64 + gc][m], m=0..7, k = ch*32+ks*8+m.
// gc -> source row: gate=(gc>>3)&3, jj=(gc&7)+8*(gc>>5), srow=gate*HD+jt*16+jj.
// Grid (32, nch), block 256 (tid -> ks=tid>>6, gc=tid&63).
// ---------------------------------------------------------------------------
__global__ __launch_bounds__(256)
void prep_wfrag(const float* __restrict__ Whh, const float* __restrict__ Wih,
                unsigned short* __restrict__ Ph, unsigned short* __restrict__ Pl,
                int nch)
{
    const int jt = blockIdx.x, ch = blockIdx.y;
    const int ks = threadIdx.x >> 6, gc = threadIdx.x & 63;
    const int gate = (gc >> 3) & 3;
    const int jj = (gc & 7) + ((gc >> 5) << 3);
    const int srow = gate * HD + jt * 16 + jj;
    const int k0 = ch * 32 + ks * 8;
    const size_t o = (size_t)jt * (64 * nch * 32) + (size_t)((ch * 4 + ks) * 64 + gc) * 8;
    #pragma unroll
    for (int m = 0; m < 8; ++m) {
        int k = k0 + m;
        float v = (k < HD) ? Whh[(size_t)srow * HD + k] : Wih[(size_t)srow * CD + (k - HD)];
        unsigned short hi = f2bf(v);
        Ph[o + m] = hi;
        Pl[o + m] = f2bf(v - bf2f(hi));
    }
}

// ---------------------------------------------------------------------------
// x prep: (N,C,T) f32 -> bf16 hi/lo planes xT[t][n][c]. One block per n.
// ---------------------------------------------------------------------------
__global__ __launch_bounds__(256)
void prep_xT(const float* __restrict__ x,
             unsigned short* __restrict__ Xh, unsigned short* __restrict__ Xl)
{
    __shared__ float tile[CD * TD];   // 43008 B, [c][t]
    const int n = blockIdx.x;
    for (int e = threadIdx.x; e < CD * TD; e += 256)
        tile[e] = x[(size_t)n * CD * TD + e];
    __syncthreads();
    for (int e = threadIdx.x; e < CD * TD; e += 256) {
        int t = e >> 6, c = e & 63;
        float v = tile[c * TD + t];
        unsigned short hi = f2bf(v);
        size_t o = ((size_t)t * NB + n) * CD + c;
        Xh[o] = hi;
        Xl[o] = f2bf(v - bf2f(hi));
    }
}

// ---------------------------------------------------------------------------
// Persistent encoder+decoder. 256 blocks x 256 threads, 1 block/CU (LDS-bound).
// Block (jt = bid&31, ng = bid>>5): tile = 64 n x 64 gate-cols. Weights LDS-
// resident; c in registers; per-step sync = 32-block monotonic-counter barrier.
// ---------------------------------------------------------------------------
__global__ __launch_bounds__(256, 1)
void lstm_persist(const unsigned short* __restrict__ WeH, const unsigned short* __restrict__ WeL,
                  const unsigned short* __restrict__ WdH, const unsigned short* __restrict__ WdL,
                  const unsigned short* __restrict__ xH, const unsigned short* __restrict__ xL,
                  const float* __restrict__ b_e, const float* __restrict__ b_d,
                  unsigned short* __restrict__ hpH, unsigned short* __restrict__ hpL, // [2][NB][HD]
                  unsigned short* __restrict__ hsH, unsigned short* __restrict__ hsL, // [DSTEPS][NB][HD]
                  unsigned* __restrict__ cnt)
{
    __shared__ unsigned short Bh[NCHE * 2048];   // 73728 B: [ch][ks][gc][8]
    __shared__ unsigned short Bl[NCHE * 2048];   // 73728 B

    const int tid  = threadIdx.x;
    const int lane = tid & 63;
    const int wid  = tid >> 6;           // 0..3
    const int wn   = wid & 1, wg = wid >> 1;
    const int jt   = blockIdx.x & 31;
    const int ng   = blockIdx.x >> 5;
    const int n0   = ng * 64;

    const int arow0 = n0 + wn * 32 + (lane & 15);   // fm=0 A row
    const int ks8   = (lane >> 4) * 8;              // k-slot offset (elems)
    const int p     = (lane >> 3) & 1;
    const int j     = jt * 16 + (lane & 7) + (wg << 3);

    // Stage encoder weight slab into LDS (linear copy, one-time).
    for (int e = tid; e < NCHE * 256; e += 256) {
        *(bf16x8*)&Bh[e * 8] = *(const bf16x8*)&WeH[(size_t)jt * (64 * KWE) + (size_t)e * 8];
        *(bf16x8*)&Bl[e * 8] = *(const bf16x8*)&WeL[(size_t)jt * (64 * KWE) + (size_t)e * 8];
    }
    __syncthreads();

    const float be0 = b_e[0 * HD + j], be1 = b_e[1 * HD + j];
    const float be2 = b_e[2 * HD + j], be3 = b_e[3 * HD + j];
    const float bd0 = b_d[0 * HD + j], bd1 = b_d[1 * HD + j];
    const float bd2 = b_d[2 * HD + j], bd3 = b_d[3 * HD + j];

    float cr[2][4] = {};                 // register-resident cell state
    unsigned tgt = 32;
    unsigned* myc = &cnt[ng * 32];       // 128B-spaced counters

    auto step = [&](auto NCHC,
                    const unsigned short* __restrict__ ahb, const unsigned short* __restrict__ alb,
                    const unsigned short* __restrict__ xh,  const unsigned short* __restrict__ xl,
                    float b0, float b1, float b2, float b3,
                    unsigned short* __restrict__ ohH, unsigned short* __restrict__ ohL)
    {
        constexpr int NCH = decltype(NCHC)::value;
        f32x4 acc[2][2] = {};
        #pragma unroll
        for (int ch = 0; ch < NCH; ++ch) {
            bf16x8 a_h[2], a_l[2];
            if (ch < NCHD) {             // h source
                size_t o = (size_t)arow0 * HD + ch * 32 + ks8;
                a_h[0] = *(const bf16x8*)&ahb[o];
                a_l[0] = *(const bf16x8*)&alb[o];
                a_h[1] = *(const bf16x8*)&ahb[o + 16 * HD];
                a_l[1] = *(const bf16x8*)&alb[o + 16 * HD];
            } else {                     // x source (encoder only)
                size_t o = (size_t)arow0 * CD + (ch - NCHD) * 32 + ks8;
                a_h[0] = *(const bf16x8*)&xh[o];
                a_l[0] = *(const bf16x8*)&xl[o];
                a_h[1] = *(const bf16x8*)&xh[o + 16 * CD];
                a_l[1] = *(const bf16x8*)&xl[o + 16 * CD];
            }
            bf16x8 b_h[2], b_l[2];
            #pragma unroll
            for (int fg = 0; fg < 2; ++fg) {
                int bi = (ch * 256 + (lane >> 4) * 64 + wg * 32 + fg * 16 + (lane & 15)) * 8;
                b_h[fg] = *(const bf16x8*)&Bh[bi];
                b_l[fg] = *(const bf16x8*)&Bl[bi];
            }
            #pragma unroll
            for (int fm = 0; fm < 2; ++fm)
                #pragma unroll
                for (int fg = 0; fg < 2; ++fg) {
                    acc[fm][fg] = __builtin_amdgcn_mfma_f32_16x16x32_bf16(a_h[fm], b_h[fg], acc[fm][fg], 0, 0, 0);
                    acc[fm][fg] = __builtin_amdgcn_mfma_f32_16x16x32_bf16(a_h[fm], b_l[fg], acc[fm][fg], 0, 0, 0);
                    acc[fm][fg] = __builtin_amdgcn_mfma_f32_16x16x32_bf16(a_l[fm], b_h[fg], acc[fm][fg], 0, 0, 0);
                }
        }
        // Epilogue: gather i,f,g,o via shfl_xor(8), gates, c in regs, h -> global.
        #pragma unroll
        for (int fm = 0; fm < 2; ++fm)
            #pragma unroll
            for (int r = 0; r < 4; ++r) {
                float v0 = acc[fm][0][r], v1 = acc[fm][1][r];
                float u0 = __shfl_xor(v0, 8, 64);
                float u1 = __shfl_xor(v1, 8, 64);
                if (p == 0) {
                    int n = n0 + wn * 32 + fm * 16 + ((lane >> 4) << 2) + r;
                    float gi = v0 + b0, gf = u0 + b1, gg = v1 + b2, go = u1 + b3;
                    float cn = sigmf(gf) * cr[fm][r] + sigmf(gi) * tanhf(gg);
                    float hn = sigmf(go) * tanhf(cn);
                    cr[fm][r] = cn;
                    unsigned short hh = f2bf(hn);
                    ohH[(size_t)n * HD + j] = hh;
                    ohL[(size_t)n * HD + j] = f2bf(hn - bf2f(hh));
                }
            }
    };

    auto ngbar = [&]() {
        __syncthreads();                 // all waves done (stores drained by barrier)
        if (tid == 0) {
            __threadfence();             // release: h writes visible device-wide
            __hip_atomic_fetch_add(myc, 1u, __ATOMIC_RELEASE, __HIP_MEMORY_SCOPE_AGENT);
            while (__hip_atomic_load(myc, __ATOMIC_ACQUIRE, __HIP_MEMORY_SCOPE_AGENT) < tgt)
                __builtin_amdgcn_s_sleep(1);
            __threadfence();             // acquire: invalidate stale cached h
        }
        tgt += 32;
        __syncthreads();
    };

    const size_t NH = (size_t)NB * HD;

    // ---- encoder: 168 steps (even count -> h_enc lands in slot 0) ----
    for (int t = 0; t < TD; ++t) {
        const unsigned short* hb = hpH + (size_t)(t & 1) * NH;
        const unsigned short* lb = hpL + (size_t)(t & 1) * NH;
        step(std::integral_constant<int, NCHE>{}, hb, lb,
             xH + (size_t)t * NB * CD, xL + (size_t)t * NB * CD,
             be0, be1, be2, be3,
             hpH + (size_t)((t + 1) & 1) * NH, hpL + (size_t)((t + 1) & 1) * NH);
        ngbar();
    }

    // ---- swap in decoder weights ----
    for (int e = tid; e < NCHD * 256; e += 256) {
        *(bf16x8*)&Bh[e * 8] = *(const bf16x8*)&WdH[(size_t)jt * (64 * HD) + (size_t)e * 8];
        *(bf16x8*)&Bl[e * 8] = *(const bf16x8*)&WdL[(size_t)jt * (64 * HD) + (size_t)e * 8];
    }
    __syncthreads();
    #pragma unroll
    for (int fm = 0; fm < 2; ++fm)
        #pragma unroll
        for (int r = 0; r < 4; ++r) cr[fm][r] = 0.f;

    // ---- decoder: 24 steps, outputs land in hs slots ----
    for (int s = 0; s < DSTEPS; ++s) {
        const unsigned short* hb = (s == 0) ? hpH : hsH + (size_t)(s - 1) * NH;
        const unsigned short* lb = (s == 0) ? hpL : hsL + (size_t)(s - 1) * NH;
        step(std::integral_constant<int, NCHD>{}, hb, lb, nullptr, nullptr,
             bd0, bd1, bd2, bd3,
             hsH + (size_t)s * NH, hsL + (size_t)s * NH);
        ngbar();
    }
}

// ---------------------------------------------------------------------------
// Dense head: out[n][o][t] = sum_k (hs_hi+hs_lo)[t][n][k] * Wd[t][o][k] + bd.
// ---------------------------------------------------------------------------
__global__ __launch_bounds__(256)
void dense_kernel(const unsigned short* __restrict__ hs_hi,
                  const unsigned short* __restrict__ hs_lo,
                  const float* __restrict__ Wd,
                  const float* __restrict__ bd,
                  float* __restrict__ out)
{
    const int t  = blockIdx.y;
    const int n0 = blockIdx.x * 64;
    const int tid = threadIdx.x;
    const int to  = tid & 15;
    const int tn  = tid >> 4;

    __shared__ __align__(16) float aT[32 * 68];
    __shared__ __align__(16) float wT[32 * 68];

    float acc[4][4] = {};

    for (int ch = 0; ch < HD / 32; ++ch) {
        const int k0 = ch * 32;
        __syncthreads();
        #pragma unroll
        for (int i = 0; i < 8; ++i) {
            int e  = tid + i * 256;
            int kk = e & 31;
            int nl = e >> 5;
            size_t hidx = ((size_t)t * NB + n0 + nl) * HD + k0 + kk;
            aT[kk * 68 + nl] = bf2f(hs_hi[hidx]) + bf2f(hs_lo[hidx]);
            wT[kk * 68 + nl] = Wd[((size_t)t * OUTC + nl) * HD + k0 + kk];
        }
        __syncthreads();
        #pragma unroll
        for (int kk = 0; kk < 32; ++kk) {
            float4 a = *reinterpret_cast<const float4*>(&aT[kk * 68 + tn * 4]);
            float4 w = *reinterpret_cast<const float4*>(&wT[kk * 68 + to * 4]);
            acc[0][0] += a.x * w.x; acc[0][1] += a.x * w.y; acc[0][2] += a.x * w.z; acc[0][3] += a.x * w.w;
            acc[1][0] += a.y * w.x; acc[1][1] += a.y * w.y; acc[1][2] += a.y * w.z; acc[1][3] += a.y * w.w;
            acc[2][0] += a.z * w.x; acc[2][1] += a.z * w.y; acc[2][2] += a.z * w.z; acc[2][3] += a.z * w.w;
            acc[3][0] += a.w * w.x; acc[3][1] += a.w * w.y; acc[3][2] += a.w * w.z; acc[3][3] += a.w * w.w;
        }
    }

    #pragma unroll
    for (int i = 0; i < 4; ++i)
        #pragma unroll
        for (int jq = 0; jq < 4; ++jq) {
            int n = n0 + tn * 4 + i;
            int o = to * 4 + jq;
            out[((size_t)n * OUTC + o) * DSTEPS + t] = acc[i][jq] + bd[t * OUTC + o];
        }
}

// ---------------------------------------------------------------------------
extern "C" void kernel_launch(void* const* d_in, const int* in_sizes, int n_in,
                              void* d_out, int out_size, void* d_ws, size_t ws_size,
                              hipStream_t stream) {
    const float* x       = (const float*)d_in[0];
    const float* W_ih_e  = (const float*)d_in[1];
    const float* W_hh_e  = (const float*)d_in[2];
    const float* b_e     = (const float*)d_in[3];
    const float* W_hh_d  = (const float*)d_in[4];
    const float* b_d     = (const float*)d_in[5];
    const float* W_dense = (const float*)d_in[6];
    const float* b_dense = (const float*)d_in[7];
    float* out = (float*)d_out;

    const size_t NH = (size_t)NB * HD;   // 262144 elems

    char* pws = (char*)d_ws;
    auto alloc = [&](size_t bytes) { char* q = pws; pws += (bytes + 255) & ~(size_t)255; return q; };
    unsigned short* WeH = (unsigned short*)alloc((size_t)GATES * KWE * 2);
    unsigned short* WeL = (unsigned short*)alloc((size_t)GATES * KWE * 2);
    unsigned short* WdH = (unsigned short*)alloc((size_t)GATES * HD * 2);
    unsigned short* WdL = (unsigned short*)alloc((size_t)GATES * HD * 2);
    unsigned short* xH  = (unsigned short*)alloc((size_t)TD * NB * CD * 2);
    unsigned short* xL  = (unsigned short*)alloc((size_t)TD * NB * CD * 2);
    unsigned short* hpH = (unsigned short*)alloc(2 * NH * 2);
    unsigned short* hpL = (unsigned short*)alloc(2 * NH * 2);
    unsigned short* hsH = (unsigned short*)alloc((size_t)DSTEPS * NH * 2);
    unsigned short* hsL = (unsigned short*)alloc((size_t)DSTEPS * NH * 2);
    unsigned*       cnt = (unsigned*)alloc(8 * 32 * sizeof(unsigned));

    // Prep (every call; deterministic)
    prep_wfrag<<<dim3(32, NCHE), dim3(256), 0, stream>>>(W_hh_e, W_ih_e, WeH, WeL, NCHE);
    prep_wfrag<<<dim3(32, NCHD), dim3(256), 0, stream>>>(W_hh_d, W_hh_d, WdH, WdL, NCHD);
    prep_xT<<<dim3(NB), dim3(256), 0, stream>>>(x, xH, xL);

    hipMemsetAsync(hpH, 0, NH * 2, stream);          // slot 0 only
    hipMemsetAsync(hpL, 0, NH * 2, stream);
    hipMemsetAsync(cnt, 0, 8 * 32 * sizeof(unsigned), stream);

    lstm_persist<<<dim3(256), dim3(256), 0, stream>>>(
        WeH, WeL, WdH, WdL, xH, xL, b_e, b_d, hpH, hpL, hsH, hsL, cnt);

    dense_kernel<<<dim3(NB / 64, DSTEPS), dim3(256), 0, stream>>>(
        hsH, hsL, W_dense, b_dense, out);
}

// Round 4
// 3314.583 us; speedup vs baseline: 1.9103x; 1.9103x over previous
//
#include <hip/hip_runtime.h>
#include <math.h>
#include <type_traits>

// Problem constants
#define NB 512     // batch
#define HD 512     // hidden
#define CD 64      // in channels
#define TD 168     // encode length
#define DSTEPS 24  // decoder steps
#define OUTC 64    // out channels
#define GATES 2048 // 4*HD
#define KWE (HD + CD)   // encoder K = 576
#define NCHE 18         // encoder K chunks (32 each)
#define NCHD 16         // decoder K chunks = LDS-resident B chunks

typedef __attribute__((ext_vector_type(8))) short bf16x8;
typedef __attribute__((ext_vector_type(4))) float f32x4;

__device__ __forceinline__ float sigmf(float x) { return 1.0f / (1.0f + expf(-x)); }
__device__ __forceinline__ float bf2f(unsigned short h) {
    return __uint_as_float(((unsigned)h) << 16);
}
__device__ __forceinline__ unsigned short f2bf(float x) {  // round-to-nearest-even
    unsigned u = __float_as_uint(x);
    return (unsigned short)((u + 0x7fffu + ((u >> 16) & 1u)) >> 16);
}
__device__ __forceinline__ unsigned packsplit(float v) {   // bf16 hi|lo packed
    unsigned short hi = f2bf(v);
    unsigned short lo = f2bf(v - bf2f(hi));
    return ((unsigned)hi << 16) | (unsigned)lo;
}

// ---------------------------------------------------------------------------
// Weight prep: split f32 into bf16 hi/lo planes, permuted + fragment-ready.
// Elem [(ch*4+ks)*64 + gc][m] holds source row gate*HD + jt*16 + jj at
// k = ch*32 + ks*8 + m, with gate=(gc>>3)&3, jj=(gc&7)+8*(gc>>5).
// ---------------------------------------------------------------------------
__global__ __launch_bounds__(256)
void prep_wfrag(const float* __restrict__ Whh, const float* __restrict__ Wih,
                unsigned short* __restrict__ Ph, unsigned short* __restrict__ Pl,
                int nch)
{
    const int jt = blockIdx.x, ch = blockIdx.y;
    const int ks = threadIdx.x >> 6, gc = threadIdx.x & 63;
    const int gate = (gc >> 3) & 3;
    const int jj = (gc & 7) + ((gc >> 5) << 3);
    const int srow = gate * HD + jt * 16 + jj;
    const int k0 = ch * 32 + ks * 8;
    const size_t o = (size_t)jt * (64 * nch * 32) + (size_t)((ch * 4 + ks) * 64 + gc) * 8;
    #pragma unroll
    for (int m = 0; m < 8; ++m) {
        int k = k0 + m;
        float v = (k < HD) ? Whh[(size_t)srow * HD + k] : Wih[(size_t)srow * CD + (k - HD)];
        unsigned short hi = f2bf(v);
        Ph[o + m] = hi;
        Pl[o + m] = f2bf(v - bf2f(hi));
    }
}

// ---------------------------------------------------------------------------
// x prep: (N,C,T) f32 -> packed hi|lo u32 planes xP[t][n][c].
// ---------------------------------------------------------------------------
__global__ __launch_bounds__(256)
void prep_xPk(const float* __restrict__ x, unsigned* __restrict__ Xp)
{
    __shared__ float tile[CD * TD];
    const int n = blockIdx.x;
    for (int e = threadIdx.x; e < CD * TD; e += 256)
        tile[e] = x[(size_t)n * CD * TD + e];
    __syncthreads();
    for (int e = threadIdx.x; e < CD * TD; e += 256) {
        int t = e >> 6, c = e & 63;
        Xp[((size_t)t * NB + n) * CD + c] = packsplit(tile[c * TD + t]);
    }
}

// ---------------------------------------------------------------------------
// Persistent encoder+decoder. 256 blocks x 256 threads (4 waves), 1 block/CU.
// Block (jt = bid>>3, ng = bid&7): tile 64n x 64gc. B (k<512) LDS-resident;
// A staged via 16KB LDS dbuf with 2-deep reg prefetch; c in registers;
// h exchanged as packed u32 via relaxed agent atomics; per-step counter
// barrier (no wbl2), acquire fence (inv only) once per step.
// ---------------------------------------------------------------------------
__global__ __launch_bounds__(256, 1)
void lstm_persist(const unsigned short* __restrict__ WeH, const unsigned short* __restrict__ WeL,
                  const unsigned short* __restrict__ WdH, const unsigned short* __restrict__ WdL,
                  const unsigned* __restrict__ xP,
                  const float* __restrict__ b_e, const float* __restrict__ b_d,
                  unsigned* __restrict__ hp,   // [2][NB*HD] packed
                  unsigned* __restrict__ hs,   // [DSTEPS][NB*HD] packed
                  unsigned* __restrict__ cnt)
{
    __shared__ unsigned short Bh[NCHD * 2048];   // 65536 B
    __shared__ unsigned short Bl[NCHD * 2048];   // 65536 B
    __shared__ unsigned short Ah[2][2048];       // 8192 B (dbuf)
    __shared__ unsigned short Al[2][2048];       // 8192 B

    const int tid  = threadIdx.x;
    const int lane = tid & 63;
    const int wid  = tid >> 6;           // 0..3
    const int wn   = wid & 1, wg = wid >> 1;
    const int jt   = blockIdx.x >> 3;    // 0..31
    const int ng   = blockIdx.x & 7;     // group == XCD (heuristic affinity)
    const int n0   = ng * 64;

    const int srow = tid >> 2;           // staging row 0..63
    const int sks  = tid & 3;            // staging k-slot 0..3
    const int rs   = lane >> 4;          // frag k-slot 0..3
    const int p    = (lane >> 3) & 1;
    const int j    = jt * 16 + (lane & 7) + (wg << 3);

    const size_t slabE = (size_t)jt * (64 * KWE);
    const size_t slabD = (size_t)jt * (64 * HD);
    const size_t NH    = (size_t)NB * HD;

    // One-time encoder B stage (chunks 0..15) into LDS.
    for (int e = tid; e < NCHD * 256; e += 256) {
        *(bf16x8*)&Bh[(size_t)e * 8] = *(const bf16x8*)&WeH[slabE + (size_t)e * 8];
        *(bf16x8*)&Bl[(size_t)e * 8] = *(const bf16x8*)&WeL[slabE + (size_t)e * 8];
    }
    __syncthreads();

    const float be0 = b_e[0 * HD + j], be1 = b_e[1 * HD + j];
    const float be2 = b_e[2 * HD + j], be3 = b_e[3 * HD + j];
    const float bd0 = b_d[0 * HD + j], bd1 = b_d[1 * HD + j];
    const float bd2 = b_d[2 * HD + j], bd3 = b_d[3 * HD + j];

    float cr[2][4] = {};
    unsigned tgt = 32;
    unsigned* myc = &cnt[ng * 32];

    auto step = [&](auto NCHC, const unsigned* __restrict__ hsrc,
                    const unsigned* __restrict__ xsrc,
                    const unsigned short* __restrict__ WtH,  // enc slab base (tail)
                    const unsigned short* __restrict__ WtL,
                    float b0, float b1, float b2, float b3,
                    unsigned* __restrict__ hdst)
    {
        constexpr int NCH = decltype(NCHC)::value;
        f32x4 acc[2][2] = {};

        // Encoder-only: prefetch B tail (chunks 16,17) into registers at step
        // start so their global latency hides under 16 LDS chunks of MFMA.
        bf16x8 tb_h[2][2], tb_l[2][2];
        if constexpr (NCH > NCHD) {
            #pragma unroll
            for (int tc = 0; tc < 2; ++tc)
                #pragma unroll
                for (int fg = 0; fg < 2; ++fg) {
                    int bi = (tc + NCHD) * 2048 + rs * 512 + (wg * 32 + fg * 16 + (lane & 15)) * 8;
                    tb_h[tc][fg] = *(const bf16x8*)&WtH[bi];
                    tb_l[tc][fg] = *(const bf16x8*)&WtL[bi];
                }
        }

        uint4 pe0, pe1, po0, po1;   // 2-deep A prefetch (even/odd chunk)
        auto issue = [&](int ch, uint4& q0, uint4& q1) {
            if (ch < NCHD) {
                const unsigned* s = &hsrc[(size_t)(n0 + srow) * HD + ch * 32 + sks * 8];
                q0 = *(const uint4*)s; q1 = *(const uint4*)(s + 4);
            } else {
                const unsigned* s = &xsrc[(size_t)(n0 + srow) * CD + (ch - NCHD) * 32 + sks * 8];
                q0 = *(const uint4*)s; q1 = *(const uint4*)(s + 4);
            }
        };
        issue(0, pe0, pe1);
        if (NCH > 1) issue(1, po0, po1);

        #pragma unroll
        for (int ch = 0; ch < NCH; ++ch) {
            const uint4 q0 = (ch & 1) ? po0 : pe0;
            const uint4 q1 = (ch & 1) ? po1 : pe1;
            bf16x8 hi, lo;
            hi[0]=(short)(q0.x>>16); lo[0]=(short)(q0.x&0xffffu);
            hi[1]=(short)(q0.y>>16); lo[1]=(short)(q0.y&0xffffu);
            hi[2]=(short)(q0.z>>16); lo[2]=(short)(q0.z&0xffffu);
            hi[3]=(short)(q0.w>>16); lo[3]=(short)(q0.w&0xffffu);
            hi[4]=(short)(q1.x>>16); lo[4]=(short)(q1.x&0xffffu);
            hi[5]=(short)(q1.y>>16); lo[5]=(short)(q1.y&0xffffu);
            hi[6]=(short)(q1.z>>16); lo[6]=(short)(q1.z&0xffffu);
            hi[7]=(short)(q1.w>>16); lo[7]=(short)(q1.w&0xffffu);
            *(bf16x8*)&Ah[ch & 1][(sks * 64 + srow) * 8] = hi;
            *(bf16x8*)&Al[ch & 1][(sks * 64 + srow) * 8] = lo;
            if (ch + 2 < NCH) {
                if (ch & 1) issue(ch + 2, po0, po1);
                else        issue(ch + 2, pe0, pe1);
            }
            // LDS-only barrier: prefetch loads stay in flight (no vmcnt drain).
            asm volatile("s_waitcnt lgkmcnt(0)\n\ts_barrier" ::: "memory");

            bf16x8 a_h[2], a_l[2], b_h[2], b_l[2];
            #pragma unroll
            for (int fm = 0; fm < 2; ++fm) {
                int ai = (rs * 64 + wn * 32 + fm * 16 + (lane & 15)) * 8;
                a_h[fm] = *(const bf16x8*)&Ah[ch & 1][ai];
                a_l[fm] = *(const bf16x8*)&Al[ch & 1][ai];
            }
            #pragma unroll
            for (int fg = 0; fg < 2; ++fg) {
                if (ch < NCHD) {
                    int bi = ch * 2048 + rs * 512 + (wg * 32 + fg * 16 + (lane & 15)) * 8;
                    b_h[fg] = *(const bf16x8*)&Bh[bi];
                    b_l[fg] = *(const bf16x8*)&Bl[bi];
                } else {
                    b_h[fg] = tb_h[ch - NCHD][fg];
                    b_l[fg] = tb_l[ch - NCHD][fg];
                }
            }
            #pragma unroll
            for (int fm = 0; fm < 2; ++fm)
                #pragma unroll
                for (int fg = 0; fg < 2; ++fg) {
                    acc[fm][fg] = __builtin_amdgcn_mfma_f32_16x16x32_bf16(a_h[fm], b_h[fg], acc[fm][fg], 0, 0, 0);
                    acc[fm][fg] = __builtin_amdgcn_mfma_f32_16x16x32_bf16(a_h[fm], b_l[fg], acc[fm][fg], 0, 0, 0);
                    acc[fm][fg] = __builtin_amdgcn_mfma_f32_16x16x32_bf16(a_l[fm], b_h[fg], acc[fm][fg], 0, 0, 0);
                }
        }

        // Epilogue: gather i,f,g,o via shfl_xor(8); gates; c in regs; h -> sc1 store.
        #pragma unroll
        for (int fm = 0; fm < 2; ++fm)
            #pragma unroll
            for (int r = 0; r < 4; ++r) {
                float v0 = acc[fm][0][r], v1 = acc[fm][1][r];
                float u0 = __shfl_xor(v0, 8, 64);
                float u1 = __shfl_xor(v1, 8, 64);
                if (p == 0) {
                    int n = n0 + wn * 32 + fm * 16 + ((lane >> 4) << 2) + r;
                    float gi = v0 + b0, gf = u0 + b1, gg = v1 + b2, go = u1 + b3;
                    float cn = sigmf(gf) * cr[fm][r] + sigmf(gi) * tanhf(gg);
                    float hn = sigmf(go) * tanhf(cn);
                    cr[fm][r] = cn;
                    __hip_atomic_store(&hdst[(size_t)n * HD + j], packsplit(hn),
                                       __ATOMIC_RELAXED, __HIP_MEMORY_SCOPE_AGENT);
                }
            }
    };

    auto ngbar = [&]() {
        __syncthreads();   // drains vmcnt: sc1 h-stores are at coherence point
        if (tid == 0) {
            __hip_atomic_fetch_add(myc, 1u, __ATOMIC_RELAXED, __HIP_MEMORY_SCOPE_AGENT);
            while (__hip_atomic_load(myc, __ATOMIC_RELAXED, __HIP_MEMORY_SCOPE_AGENT) < tgt)
                __builtin_amdgcn_s_sleep(1);
        }
        __syncthreads();
        __builtin_amdgcn_fence(__ATOMIC_ACQUIRE, "agent");  // inv stale L1/L2 lines
        tgt += 32;
    };

    // ---- encoder: 168 steps (even count -> h_enc lands in slot 0) ----
    for (int t = 0; t < TD; ++t) {
        step(std::integral_constant<int, NCHE>{},
             hp + (size_t)(t & 1) * NH, xP + (size_t)t * NB * CD,
             WeH + slabE, WeL + slabE,
             be0, be1, be2, be3,
             hp + (size_t)((t + 1) & 1) * NH);
        ngbar();
    }

    // ---- swap in decoder weights (block-local; synced by last ngbar) ----
    for (int e = tid; e < NCHD * 256; e += 256) {
        *(bf16x8*)&Bh[(size_t)e * 8] = *(const bf16x8*)&WdH[slabD + (size_t)e * 8];
        *(bf16x8*)&Bl[(size_t)e * 8] = *(const bf16x8*)&WdL[slabD + (size_t)e * 8];
    }
    __syncthreads();
    #pragma unroll
    for (int fm = 0; fm < 2; ++fm)
        #pragma unroll
        for (int r = 0; r < 4; ++r) cr[fm][r] = 0.f;

    // ---- decoder: 24 steps, outputs land in hs slots ----
    for (int s = 0; s < DSTEPS; ++s) {
        const unsigned* hb = (s == 0) ? hp : hs + (size_t)(s - 1) * NH;
        step(std::integral_constant<int, NCHD>{}, hb, hb,
             WdH + slabD, WdL + slabD,
             bd0, bd1, bd2, bd3,
             hs + (size_t)s * NH);
        ngbar();
    }
}

// ---------------------------------------------------------------------------
// Dense head: out[n][o][t] = sum_k unpack(hs[t][n][k]) * Wd[t][o][k] + bd.
// ---------------------------------------------------------------------------
__global__ __launch_bounds__(256)
void dense_kernel(const unsigned* __restrict__ hsP,
                  const float* __restrict__ Wd,
                  const float* __restrict__ bd,
                  float* __restrict__ out)
{
    const int t  = blockIdx.y;
    const int n0 = blockIdx.x * 64;
    const int tid = threadIdx.x;
    const int to  = tid & 15;
    const int tn  = tid >> 4;

    __shared__ __align__(16) float aT[32 * 68];
    __shared__ __align__(16) float wT[32 * 68];

    float acc[4][4] = {};

    for (int ch = 0; ch < HD / 32; ++ch) {
        const int k0 = ch * 32;
        __syncthreads();
        #pragma unroll
        for (int i = 0; i < 8; ++i) {
            int e  = tid + i * 256;
            int kk = e & 31;
            int nl = e >> 5;
            unsigned v = hsP[((size_t)t * NB + n0 + nl) * HD + k0 + kk];
            aT[kk * 68 + nl] = bf2f((unsigned short)(v >> 16)) + bf2f((unsigned short)(v & 0xffffu));
            wT[kk * 68 + nl] = Wd[((size_t)t * OUTC + nl) * HD + k0 + kk];
        }
        __syncthreads();
        #pragma unroll
        for (int kk = 0; kk < 32; ++kk) {
            float4 a = *reinterpret_cast<const float4*>(&aT[kk * 68 + tn * 4]);
            float4 w = *reinterpret_cast<const float4*>(&wT[kk * 68 + to * 4]);
            acc[0][0] += a.x * w.x; acc[0][1] += a.x * w.y; acc[0][2] += a.x * w.z; acc[0][3] += a.x * w.w;
            acc[1][0] += a.y * w.x; acc[1][1] += a.y * w.y; acc[1][2] += a.y * w.z; acc[1][3] += a.y * w.w;
            acc[2][0] += a.z * w.x; acc[2][1] += a.z * w.y; acc[2][2] += a.z * w.z; acc[2][3] += a.z * w.w;
            acc[3][0] += a.w * w.x; acc[3][1] += a.w * w.y; acc[3][2] += a.w * w.z; acc[3][3] += a.w * w.w;
        }
    }

    #pragma unroll
    for (int i = 0; i < 4; ++i)
        #pragma unroll
        for (int jq = 0; jq < 4; ++jq) {
            int n = n0 + tn * 4 + i;
            int o = to * 4 + jq;
            out[((size_t)n * OUTC + o) * DSTEPS + t] = acc[i][jq] + bd[t * OUTC + o];
        }
}

// ---------------------------------------------------------------------------
extern "C" void kernel_launch(void* const* d_in, const int* in_sizes, int n_in,
                              void* d_out, int out_size, void* d_ws, size_t ws_size,
                              hipStream_t stream) {
    const float* x       = (const float*)d_in[0];
    const float* W_ih_e  = (const float*)d_in[1];
    const float* W_hh_e  = (const float*)d_in[2];
    const float* b_e     = (const float*)d_in[3];
    const float* W_hh_d  = (const float*)d_in[4];
    const float* b_d     = (const float*)d_in[5];
    const float* W_dense = (const float*)d_in[6];
    const float* b_dense = (const float*)d_in[7];
    float* out = (float*)d_out;

    const size_t NH = (size_t)NB * HD;   // 262144 elems

    char* pws = (char*)d_ws;
    auto alloc = [&](size_t bytes) { char* q = pws; pws += (bytes + 255) & ~(size_t)255; return q; };
    unsigned short* WeH = (unsigned short*)alloc((size_t)GATES * KWE * 2);
    unsigned short* WeL = (unsigned short*)alloc((size_t)GATES * KWE * 2);
    unsigned short* WdH = (unsigned short*)alloc((size_t)GATES * HD * 2);
    unsigned short* WdL = (unsigned short*)alloc((size_t)GATES * HD * 2);
    unsigned*       xPk = (unsigned*)alloc((size_t)TD * NB * CD * 4);
    unsigned*       hp  = (unsigned*)alloc(2 * NH * 4);
    unsigned*       hs  = (unsigned*)alloc((size_t)DSTEPS * NH * 4);
    unsigned*       cnt = (unsigned*)alloc(8 * 32 * sizeof(unsigned));

    // Prep (every call; deterministic)
    prep_wfrag<<<dim3(32, NCHE), dim3(256), 0, stream>>>(W_hh_e, W_ih_e, WeH, WeL, NCHE);
    prep_wfrag<<<dim3(32, NCHD), dim3(256), 0, stream>>>(W_hh_d, W_hh_d, WdH, WdL, NCHD);
    prep_xPk<<<dim3(NB), dim3(256), 0, stream>>>(x, xPk);

    hipMemsetAsync(hp, 0, NH * 4, stream);                 // slot 0 = zeros
    hipMemsetAsync(cnt, 0, 8 * 32 * sizeof(unsigned), stream);

    lstm_persist<<<dim3(256), dim3(256), 0, stream>>>(
        WeH, WeL, WdH, WdL, xPk, b_e, b_d, hp, hs, cnt);

    dense_kernel<<<dim3(NB / 64, DSTEPS), dim3(256), 0, stream>>>(
        hs, W_dense, b_dense, out);
}